// Round 3
// baseline (4578.847 us; speedup 1.0000x reference)
//
#include <hip/hip_runtime.h>
#include <math.h>

// Problem constants
#define BTOT   4096
#define CIN    3
#define TIN    64
#define SIN    128
#define HH     129      // GRU hidden / action dim
#define H3     387      // 3*H
#define INGRU  124      // S-4
#define TGRU   60       // T-4
#define FEATN  258
#define FEATP  260

// ws layout (float offsets)
#define SEQ_OFF   0                          // [4096][60][124]
#define G_OFF     (SEQ_OFF + 4096*60*124)    // [4096][129]
#define WHHP_OFF  (G_OFF + 4096*129)         // [387][132]
#define MUWP_OFF  (WHHP_OFF + 387*132)       // [129][260]
#define LSWP_OFF  (MUWP_OFF + 129*260)       // [129][260]
#define WS_FLOATS (LSWP_OFF + 129*260)

// ---------------------------------------------------------------------------
// Prep: zero-pad Whh rows 129->132, fc weights rows 258->260 (16B-aligned rows)
// ---------------------------------------------------------------------------
__global__ __launch_bounds__(256) void prep_pad(
    const float* __restrict__ Whh, const float* __restrict__ muw,
    const float* __restrict__ lsw, float* __restrict__ ws)
{
    int idx = blockIdx.x * 256 + threadIdx.x;
    const int N1 = 387 * 132;
    const int N2 = 129 * 260;
    if (idx < N1) {
        int n = idx / 132, k = idx - n * 132;
        ws[WHHP_OFF + idx] = (k < 129) ? Whh[n * 129 + k] : 0.f;
    } else if (idx < N1 + N2) {
        int i = idx - N1; int j = i / 260, k = i - j * 260;
        ws[MUWP_OFF + i] = (k < 258) ? muw[j * 258 + k] : 0.f;
    } else if (idx < N1 + 2 * N2) {
        int i = idx - N1 - N2; int j = i / 260, k = i - j * 260;
        ws[LSWP_OFF + i] = (k < 258) ? lsw[j * 258 + k] : 0.f;
    }
}

// ---------------------------------------------------------------------------
// Fused conv1+conv2 (both VALID 3x3, leaky) -> seq[B][60][124]
// One block per (batch, T-tile of 10 output rows)
// ---------------------------------------------------------------------------
__global__ __launch_bounds__(256) void conv_fused(
    const float* __restrict__ x,
    const float* __restrict__ w1, const float* __restrict__ b1,
    const float* __restrict__ w2, const float* __restrict__ b2,
    float* __restrict__ seq)
{
    __shared__ __attribute__((aligned(16))) float xt[3 * 14 * 128];
    __shared__ __attribute__((aligned(16))) float h1t[6 * 12 * 128];
    __shared__ float w1s[162];
    __shared__ float w2s[54];
    __shared__ float b1s[6];
    __shared__ float b2s;

    const int tid  = threadIdx.x;
    const int tile = blockIdx.x;   // 0..5
    const int bb   = blockIdx.y;   // batch
    const int T0   = tile * 10;

    if (tid < 162)                  w1s[tid] = w1[tid];
    if (tid >= 192 && tid < 246)    w2s[tid - 192] = w2[tid - 192];
    if (tid >= 248 && tid < 254)    b1s[tid - 248] = b1[tid - 248];
    if (tid == 255)                 b2s = b2[0];

    const float* xb = x + (size_t)bb * CIN * TIN * SIN;
    for (int i = tid; i < 3 * 14 * 128; i += 256) {
        int c = i / (14 * 128);
        int rem = i - c * (14 * 128);
        int t = rem >> 7;
        int s = rem & 127;
        xt[i] = xb[(c * TIN + T0 + t) * SIN + s];
    }
    __syncthreads();

    // conv1 + leaky -> h1 tile [6][12][126] (stride 128)
    for (int i = tid; i < 6 * 12 * 126; i += 256) {
        int o = i / (12 * 126);
        int rem = i - o * (12 * 126);
        int t = rem / 126;
        int s = rem - t * 126;
        float acc = b1s[o];
        #pragma unroll
        for (int c = 0; c < 3; ++c)
            #pragma unroll
            for (int kt = 0; kt < 3; ++kt)
                #pragma unroll
                for (int ks = 0; ks < 3; ++ks)
                    acc += xt[(c * 14 + t + kt) * 128 + (s + ks)] *
                           w1s[(o * 3 + c) * 9 + kt * 3 + ks];
        h1t[(o * 12 + t) * 128 + s] = (acc >= 0.f) ? acc : 0.01f * acc;
    }
    __syncthreads();

    // conv2 + leaky -> seq rows T0..T0+9
    for (int i = tid; i < 10 * 124; i += 256) {
        int t = i / 124;
        int s = i - t * 124;
        float acc = b2s;
        #pragma unroll
        for (int o = 0; o < 6; ++o)
            #pragma unroll
            for (int kt = 0; kt < 3; ++kt)
                #pragma unroll
                for (int ks = 0; ks < 3; ++ks)
                    acc += h1t[(o * 12 + t + kt) * 128 + (s + ks)] *
                           w2s[o * 9 + kt * 3 + ks];
        float v = (acc >= 0.f) ? acc : 0.01f * acc;
        seq[((size_t)bb * 60 + T0 + t) * 124 + s] = v;
    }
}

// ---------------------------------------------------------------------------
// GRU: 256 blocks x 256 threads, 16 batch rows per block, loop t=0..59.
// Per step: phase1 computes gi (xs . Wih) and gh (h . Whhp) for all 387 gate
// outputs with q-blocking x3 (each LDS float4 read feeds 12 FMAs); phase2
// applies gate nonlinearities and updates h in LDS. Finally g = leaky(h_T).
// ---------------------------------------------------------------------------
__global__ __launch_bounds__(256) void gru_kernel(
    const float* __restrict__ seq, const float* __restrict__ Wih,
    const float* __restrict__ Whhp,
    const float* __restrict__ bih, const float* __restrict__ bhh,
    float* __restrict__ g_out)
{
    __shared__ __attribute__((aligned(16))) float xs[16 * 124];   // stride 124
    __shared__ __attribute__((aligned(16))) float hs[16 * 132];   // stride 132, cols 129..131 = 0
    __shared__ float Sbuf[16 * 258];  // combined r,z pre-activations
    __shared__ float GIN[16 * 129];   // i_n
    __shared__ float GHN[16 * 129];   // h_n

    const int tid = threadIdx.x;
    const int b0  = blockIdx.x * 16;

    for (int i = tid; i < 16 * 132; i += 256) hs[i] = 0.f;

    for (int t = 0; t < 60; ++t) {
        // load xs for this step
        for (int i = tid; i < 16 * 124; i += 256) {
            int r = i / 124;
            int k = i - r * 124;
            xs[i] = seq[((size_t)(b0 + r) * 60 + t) * 124 + k];
        }
        __syncthreads();

        // phase1: 2064 tasks = 16 rows x 129 q-groups (3 gate rows each)
        for (int idx = tid; idx < 2064; idx += 256) {
            int r  = idx & 15;
            int gq = idx >> 4;          // [0,129)
            int q0 = gq * 3;

            float a0 = 0.f, a1 = 0.f, a2 = 0.f;   // gi accumulators
            float g0 = 0.f, g1 = 0.f, g2 = 0.f;   // gh accumulators

            const float4* xv = (const float4*)(xs + r * 124);
            const float4* wa = (const float4*)(Wih + (size_t)q0 * 124);
            const float4* wb = (const float4*)(Wih + (size_t)(q0 + 1) * 124);
            const float4* wc = (const float4*)(Wih + (size_t)(q0 + 2) * 124);
            for (int k = 0; k < 31; ++k) {
                float4 xk = xv[k];
                float4 A = wa[k], B = wb[k], C = wc[k];
                a0 += xk.x * A.x + xk.y * A.y + xk.z * A.z + xk.w * A.w;
                a1 += xk.x * B.x + xk.y * B.y + xk.z * B.z + xk.w * B.w;
                a2 += xk.x * C.x + xk.y * C.y + xk.z * C.z + xk.w * C.w;
            }
            const float4* hv = (const float4*)(hs + r * 132);
            const float4* ha = (const float4*)(Whhp + (size_t)q0 * 132);
            const float4* hb = (const float4*)(Whhp + (size_t)(q0 + 1) * 132);
            const float4* hc = (const float4*)(Whhp + (size_t)(q0 + 2) * 132);
            for (int k = 0; k < 33; ++k) {
                float4 hk = hv[k];
                float4 A = ha[k], B = hb[k], C = hc[k];
                g0 += hk.x * A.x + hk.y * A.y + hk.z * A.z + hk.w * A.w;
                g1 += hk.x * B.x + hk.y * B.y + hk.z * B.z + hk.w * B.w;
                g2 += hk.x * C.x + hk.y * C.y + hk.z * C.z + hk.w * C.w;
            }

            if (gq < 86) {  // q0..q0+2 all < 258 : r,z gates (sum gi+gh)
                Sbuf[r * 258 + q0]     = a0 + g0 + bih[q0]     + bhh[q0];
                Sbuf[r * 258 + q0 + 1] = a1 + g1 + bih[q0 + 1] + bhh[q0 + 1];
                Sbuf[r * 258 + q0 + 2] = a2 + g2 + bih[q0 + 2] + bhh[q0 + 2];
            } else {        // n gate: keep gi / gh separate
                int j0 = q0 - 258;
                GIN[r * 129 + j0]     = a0 + bih[q0];
                GIN[r * 129 + j0 + 1] = a1 + bih[q0 + 1];
                GIN[r * 129 + j0 + 2] = a2 + bih[q0 + 2];
                GHN[r * 129 + j0]     = g0 + bhh[q0];
                GHN[r * 129 + j0 + 1] = g1 + bhh[q0 + 1];
                GHN[r * 129 + j0 + 2] = g2 + bhh[q0 + 2];
            }
        }
        __syncthreads();

        // phase2: gate nonlinearities + h update (each (r,j) owned by 1 thread)
        for (int idx = tid; idx < 16 * 129; idx += 256) {
            int r = idx & 15;
            int j = idx >> 4;
            float rr = 1.f / (1.f + __expf(-Sbuf[r * 258 + j]));
            float zz = 1.f / (1.f + __expf(-Sbuf[r * 258 + 129 + j]));
            float nn = tanhf(GIN[r * 129 + j] + rr * GHN[r * 129 + j]);
            float ho = hs[r * 132 + j];
            hs[r * 132 + j] = (1.f - zz) * nn + zz * ho;
        }
        __syncthreads();
    }

    // g = leaky(h_T)
    for (int idx = tid; idx < 16 * 129; idx += 256) {
        int r = idx & 15;
        int j = idx >> 4;
        float v = hs[r * 132 + j];
        g_out[(size_t)(b0 + r) * 129 + j] = (v >= 0.f) ? v : 0.01f * v;
    }
}

// ---------------------------------------------------------------------------
// Head: feat=[g,w] (258) -> mu, log_std (129 each) -> sample, tanh, log_pi,
// normalize. 256 blocks x 256 threads, 16 rows/block.
// ---------------------------------------------------------------------------
__global__ __launch_bounds__(256) void head_kernel(
    const float* __restrict__ gbuf, const float* __restrict__ wvec,
    const float* __restrict__ eps,
    const float* __restrict__ muwp, const float* __restrict__ lswp,
    const float* __restrict__ mub,  const float* __restrict__ lsb,
    float* __restrict__ out)
{
    __shared__ __attribute__((aligned(16))) float feat[16 * 260];
    __shared__ float PA[16 * 130];
    __shared__ float TERM[16 * 130];
    __shared__ float ROWSUM[16];
    __shared__ float ROWLOG[16];

    const int tid = threadIdx.x;
    const int b0  = blockIdx.x * 16;

    for (int i = tid; i < 16 * 260; i += 256) {
        int r = i / 260;
        int k = i - r * 260;
        float v = 0.f;
        if (k < 129)       v = gbuf[(size_t)(b0 + r) * 129 + k];
        else if (k < 258)  v = wvec[(size_t)(b0 + r) * 129 + (k - 129)];
        feat[i] = v;
    }
    __syncthreads();

    for (int idx = tid; idx < 16 * 129; idx += 256) {
        int r = idx & 15;
        int j = idx >> 4;
        const float4* fv = (const float4*)(feat + r * 260);
        const float4* mw = (const float4*)(muwp + (size_t)j * 260);
        const float4* lw = (const float4*)(lswp + (size_t)j * 260);
        float am = 0.f, al = 0.f;
        for (int k = 0; k < 65; ++k) {
            float4 f = fv[k];
            float4 m = mw[k];
            float4 l = lw[k];
            am += f.x * m.x + f.y * m.y + f.z * m.z + f.w * m.w;
            al += f.x * l.x + f.y * l.y + f.z * l.z + f.w * l.w;
        }
        float mu = am + mub[j];
        float ls = fminf(fmaxf(al + lsb[j], -20.f), 2.f);
        float sd = expf(ls);
        float e  = eps[(size_t)(b0 + r) * 129 + j];
        float xv = mu + sd * e;
        float pa = tanhf(xv);
        float tt = (xv - mu) / sd;
        float term = -0.5f * tt * tt - ls - 0.91893853320467274f
                     - logf(1.f - pa * pa + 1e-6f);
        PA[r * 130 + j]   = pa;
        TERM[r * 130 + j] = term;
    }
    __syncthreads();

    {
        int r = tid >> 4;
        int i = tid & 15;
        float sp = 0.f, st = 0.f;
        for (int j = i; j < 129; j += 16) {
            sp += PA[r * 130 + j];
            st += TERM[r * 130 + j];
        }
        for (int off = 8; off > 0; off >>= 1) {
            sp += __shfl_down(sp, off, 16);
            st += __shfl_down(st, off, 16);
        }
        if (i == 0) { ROWSUM[r] = sp + 129.f; ROWLOG[r] = st; }
    }
    __syncthreads();

    for (int idx = tid; idx < 16 * 129; idx += 256) {
        int r = idx & 15;
        int j = idx >> 4;
        out[(size_t)(b0 + r) * 129 + j] = (PA[r * 130 + j] + 1.f) / ROWSUM[r];
    }
    if (tid < 16)
        out[(size_t)4096 * 129 + b0 + tid] = ROWLOG[tid];
}

// ---------------------------------------------------------------------------
extern "C" void kernel_launch(void* const* d_in, const int* in_sizes, int n_in,
                              void* d_out, int out_size, void* d_ws, size_t ws_size,
                              hipStream_t stream)
{
    const float* x   = (const float*)d_in[0];
    const float* wv  = (const float*)d_in[1];
    const float* eps = (const float*)d_in[2];
    const float* c1w = (const float*)d_in[3];
    const float* c1b = (const float*)d_in[4];
    const float* c2w = (const float*)d_in[5];
    const float* c2b = (const float*)d_in[6];
    const float* Wih = (const float*)d_in[7];
    const float* Whh = (const float*)d_in[8];
    const float* bih = (const float*)d_in[9];
    const float* bhh = (const float*)d_in[10];
    const float* muw = (const float*)d_in[11];
    const float* mub = (const float*)d_in[12];
    const float* lsw = (const float*)d_in[13];
    const float* lsb = (const float*)d_in[14];

    float* ws   = (float*)d_ws;
    float* seq  = ws + SEQ_OFF;
    float* g    = ws + G_OFF;
    float* whhp = ws + WHHP_OFF;
    float* muwp = ws + MUWP_OFF;
    float* lswp = ws + LSWP_OFF;
    float* outp = (float*)d_out;

    const int prep_elems = 387 * 132 + 2 * (129 * 260);
    prep_pad<<<(prep_elems + 255) / 256, 256, 0, stream>>>(Whh, muw, lsw, ws);
    conv_fused<<<dim3(6, BTOT), 256, 0, stream>>>(x, c1w, c1b, c2w, c2b, seq);
    gru_kernel<<<BTOT / 16, 256, 0, stream>>>(seq, Wih, whhp, bih, bhh, g);
    head_kernel<<<BTOT / 16, 256, 0, stream>>>(g, wv, eps, muwp, lswp, mub, lsb, outp);
}

// Round 4
// 3642.339 us; speedup vs baseline: 1.2571x; 1.2571x over previous
//
#include <hip/hip_runtime.h>
#include <math.h>

// Problem constants
#define BTOT   4096
#define CIN    3
#define TIN    64
#define SIN    128

// ws layout (float offsets)
#define SEQ_OFF   0                          // [4096][60][124]
#define G_OFF     (SEQ_OFF + 4096*60*124)    // [4096][129]
#define WHHP_OFF  (G_OFF + 4096*129)         // [387][132]
#define MUWP_OFF  (WHHP_OFF + 387*132)       // [129][260]
#define LSWP_OFF  (MUWP_OFF + 129*260)       // [129][260]

// ---------------------------------------------------------------------------
// Prep: zero-pad Whh rows 129->132, fc weights rows 258->260 (16B-aligned rows)
// ---------------------------------------------------------------------------
__global__ __launch_bounds__(256) void prep_pad(
    const float* __restrict__ Whh, const float* __restrict__ muw,
    const float* __restrict__ lsw, float* __restrict__ ws)
{
    int idx = blockIdx.x * 256 + threadIdx.x;
    const int N1 = 387 * 132;
    const int N2 = 129 * 260;
    if (idx < N1) {
        int n = idx / 132, k = idx - n * 132;
        ws[WHHP_OFF + idx] = (k < 129) ? Whh[n * 129 + k] : 0.f;
    } else if (idx < N1 + N2) {
        int i = idx - N1; int j = i / 260, k = i - j * 260;
        ws[MUWP_OFF + i] = (k < 258) ? muw[j * 258 + k] : 0.f;
    } else if (idx < N1 + 2 * N2) {
        int i = idx - N1 - N2; int j = i / 260, k = i - j * 260;
        ws[LSWP_OFF + i] = (k < 258) ? lsw[j * 258 + k] : 0.f;
    }
}

// ---------------------------------------------------------------------------
// Fused conv1+conv2 (both VALID 3x3, leaky) -> seq[B][60][124]
// ---------------------------------------------------------------------------
__global__ __launch_bounds__(256) void conv_fused(
    const float* __restrict__ x,
    const float* __restrict__ w1, const float* __restrict__ b1,
    const float* __restrict__ w2, const float* __restrict__ b2,
    float* __restrict__ seq)
{
    __shared__ __attribute__((aligned(16))) float xt[3 * 14 * 128];
    __shared__ __attribute__((aligned(16))) float h1t[6 * 12 * 128];
    __shared__ float w1s[162];
    __shared__ float w2s[54];
    __shared__ float b1s[6];
    __shared__ float b2s;

    const int tid  = threadIdx.x;
    const int tile = blockIdx.x;   // 0..5
    const int bb   = blockIdx.y;   // batch
    const int T0   = tile * 10;

    if (tid < 162)                  w1s[tid] = w1[tid];
    if (tid >= 192 && tid < 246)    w2s[tid - 192] = w2[tid - 192];
    if (tid >= 248 && tid < 254)    b1s[tid - 248] = b1[tid - 248];
    if (tid == 255)                 b2s = b2[0];

    const float* xb = x + (size_t)bb * CIN * TIN * SIN;
    for (int i = tid; i < 3 * 14 * 128; i += 256) {
        int c = i / (14 * 128);
        int rem = i - c * (14 * 128);
        int t = rem >> 7;
        int s = rem & 127;
        xt[i] = xb[(c * TIN + T0 + t) * SIN + s];
    }
    __syncthreads();

    for (int i = tid; i < 6 * 12 * 126; i += 256) {
        int o = i / (12 * 126);
        int rem = i - o * (12 * 126);
        int t = rem / 126;
        int s = rem - t * 126;
        float acc = b1s[o];
        #pragma unroll
        for (int c = 0; c < 3; ++c)
            #pragma unroll
            for (int kt = 0; kt < 3; ++kt)
                #pragma unroll
                for (int ks = 0; ks < 3; ++ks)
                    acc += xt[(c * 14 + t + kt) * 128 + (s + ks)] *
                           w1s[(o * 3 + c) * 9 + kt * 3 + ks];
        h1t[(o * 12 + t) * 128 + s] = (acc >= 0.f) ? acc : 0.01f * acc;
    }
    __syncthreads();

    for (int i = tid; i < 10 * 124; i += 256) {
        int t = i / 124;
        int s = i - t * 124;
        float acc = b2s;
        #pragma unroll
        for (int o = 0; o < 6; ++o)
            #pragma unroll
            for (int kt = 0; kt < 3; ++kt)
                #pragma unroll
                for (int ks = 0; ks < 3; ++ks)
                    acc += h1t[(o * 12 + t + kt) * 128 + (s + ks)] *
                           w2s[o * 9 + kt * 3 + ks];
        float v = (acc >= 0.f) ? acc : 0.01f * acc;
        seq[((size_t)bb * 60 + T0 + t) * 124 + s] = v;
    }
}

// ---------------------------------------------------------------------------
// GRU: 256 blocks x 768 threads, 16 batch rows per block, t=0..59.
// Register blocking: thread = (part: gi|gh, rowg: 8 rows, qg: 3 gate rows).
// Each weight float4 read feeds 8 rows (16x less L2 weight traffic).
// Task groups padded to 192 slots (3 waves) so no wave mixes branches.
// ---------------------------------------------------------------------------
__global__ __launch_bounds__(768) void gru_kernel(
    const float* __restrict__ seq, const float* __restrict__ Wih,
    const float* __restrict__ Whhp,
    const float* __restrict__ bih, const float* __restrict__ bhh,
    float* __restrict__ g_out)
{
    __shared__ __attribute__((aligned(16))) float xs[16 * 124];   // 31 f4/row
    __shared__ __attribute__((aligned(16))) float hs[16 * 132];   // 33 f4/row, cols 129..131 = 0
    __shared__ float GIb[16 * 388];   // gi partials (stride 388)
    __shared__ float GHb[16 * 388];   // gh partials
    __shared__ float bihS[387];
    __shared__ float bhhS[387];

    const int tid = threadIdx.x;
    const int b0  = blockIdx.x * 16;

    for (int i = tid; i < 16 * 132; i += 768) hs[i] = 0.f;
    if (tid < 387) { bihS[tid] = bih[tid]; bhhS[tid] = bhh[tid]; }

    // task decode: 4 groups x 192 slots (wave-aligned), active if slot < 129
    const int g      = tid / 192;      // 0..3
    const int within = tid - g * 192;  // 0..191
    const int part   = g >> 1;         // 0 = gi (x@Wih), 1 = gh (h@Whh)
    const int r0     = (g & 1) * 8;    // row group base
    const int q0     = within * 3;     // gate-row base (within < 129)
    const bool active = (within < 129);

    for (int t = 0; t < 60; ++t) {
        // stage xs for this step (496 float4)
        for (int i = tid; i < 496; i += 768) {
            int r = i / 31;
            int k = i - r * 31;
            ((float4*)xs)[i] =
                *(const float4*)(seq + ((size_t)(b0 + r) * 60 + t) * 124 + 4 * k);
        }
        __syncthreads();

        if (active) {
            float acc0[8], acc1[8], acc2[8];
            #pragma unroll
            for (int rr = 0; rr < 8; ++rr) { acc0[rr] = 0.f; acc1[rr] = 0.f; acc2[rr] = 0.f; }

            if (part == 0) {
                const float4* wa = (const float4*)(Wih + (size_t)q0 * 124);
                for (int k = 0; k < 31; ++k) {
                    float4 A = wa[k], B = wa[31 + k], C = wa[62 + k];
                    #pragma unroll
                    for (int rr = 0; rr < 8; ++rr) {
                        float4 xv = ((const float4*)(xs + (r0 + rr) * 124))[k];
                        acc0[rr] += A.x * xv.x + A.y * xv.y + A.z * xv.z + A.w * xv.w;
                        acc1[rr] += B.x * xv.x + B.y * xv.y + B.z * xv.z + B.w * xv.w;
                        acc2[rr] += C.x * xv.x + C.y * xv.y + C.z * xv.z + C.w * xv.w;
                    }
                }
                #pragma unroll
                for (int rr = 0; rr < 8; ++rr) {
                    GIb[(r0 + rr) * 388 + q0]     = acc0[rr];
                    GIb[(r0 + rr) * 388 + q0 + 1] = acc1[rr];
                    GIb[(r0 + rr) * 388 + q0 + 2] = acc2[rr];
                }
            } else {
                const float4* wa = (const float4*)(Whhp + (size_t)q0 * 132);
                for (int k = 0; k < 33; ++k) {
                    float4 A = wa[k], B = wa[33 + k], C = wa[66 + k];
                    #pragma unroll
                    for (int rr = 0; rr < 8; ++rr) {
                        float4 hv = ((const float4*)(hs + (r0 + rr) * 132))[k];
                        acc0[rr] += A.x * hv.x + A.y * hv.y + A.z * hv.z + A.w * hv.w;
                        acc1[rr] += B.x * hv.x + B.y * hv.y + B.z * hv.z + B.w * hv.w;
                        acc2[rr] += C.x * hv.x + C.y * hv.y + C.z * hv.z + C.w * hv.w;
                    }
                }
                #pragma unroll
                for (int rr = 0; rr < 8; ++rr) {
                    GHb[(r0 + rr) * 388 + q0]     = acc0[rr];
                    GHb[(r0 + rr) * 388 + q0 + 1] = acc1[rr];
                    GHb[(r0 + rr) * 388 + q0 + 2] = acc2[rr];
                }
            }
        }
        __syncthreads();

        // phase2: gates + h update
        for (int i2 = tid; i2 < 16 * 129; i2 += 768) {
            int r = i2 & 15;
            int j = i2 >> 4;
            float pr  = GIb[r * 388 + j]       + GHb[r * 388 + j]       + bihS[j]       + bhhS[j];
            float pz  = GIb[r * 388 + 129 + j] + GHb[r * 388 + 129 + j] + bihS[129 + j] + bhhS[129 + j];
            float gin = GIb[r * 388 + 258 + j] + bihS[258 + j];
            float ghn = GHb[r * 388 + 258 + j] + bhhS[258 + j];
            float rr_ = 1.f / (1.f + __expf(-pr));
            float zz  = 1.f / (1.f + __expf(-pz));
            float nn  = tanhf(gin + rr_ * ghn);
            float ho  = hs[r * 132 + j];
            hs[r * 132 + j] = (1.f - zz) * nn + zz * ho;
        }
        __syncthreads();
    }

    // g = leaky(h_T)
    for (int i2 = tid; i2 < 16 * 129; i2 += 768) {
        int r = i2 & 15;
        int j = i2 >> 4;
        float v = hs[r * 132 + j];
        g_out[(size_t)(b0 + r) * 129 + j] = (v >= 0.f) ? v : 0.01f * v;
    }
}

// ---------------------------------------------------------------------------
// Head: feat=[g,w] (258) -> mu, log_std -> sample, tanh, log_pi, normalize.
// ---------------------------------------------------------------------------
__global__ __launch_bounds__(256) void head_kernel(
    const float* __restrict__ gbuf, const float* __restrict__ wvec,
    const float* __restrict__ eps,
    const float* __restrict__ muwp, const float* __restrict__ lswp,
    const float* __restrict__ mub,  const float* __restrict__ lsb,
    float* __restrict__ out)
{
    __shared__ __attribute__((aligned(16))) float feat[16 * 260];
    __shared__ float PA[16 * 130];
    __shared__ float TERM[16 * 130];
    __shared__ float ROWSUM[16];
    __shared__ float ROWLOG[16];

    const int tid = threadIdx.x;
    const int b0  = blockIdx.x * 16;

    for (int i = tid; i < 16 * 260; i += 256) {
        int r = i / 260;
        int k = i - r * 260;
        float v = 0.f;
        if (k < 129)       v = gbuf[(size_t)(b0 + r) * 129 + k];
        else if (k < 258)  v = wvec[(size_t)(b0 + r) * 129 + (k - 129)];
        feat[i] = v;
    }
    __syncthreads();

    for (int idx = tid; idx < 16 * 129; idx += 256) {
        int r = idx & 15;
        int j = idx >> 4;
        const float4* fv = (const float4*)(feat + r * 260);
        const float4* mw = (const float4*)(muwp + (size_t)j * 260);
        const float4* lw = (const float4*)(lswp + (size_t)j * 260);
        float am = 0.f, al = 0.f;
        for (int k = 0; k < 65; ++k) {
            float4 f = fv[k];
            float4 m = mw[k];
            float4 l = lw[k];
            am += f.x * m.x + f.y * m.y + f.z * m.z + f.w * m.w;
            al += f.x * l.x + f.y * l.y + f.z * l.z + f.w * l.w;
        }
        float mu = am + mub[j];
        float ls = fminf(fmaxf(al + lsb[j], -20.f), 2.f);
        float sd = expf(ls);
        float e  = eps[(size_t)(b0 + r) * 129 + j];
        float xv = mu + sd * e;
        float pa = tanhf(xv);
        float tt = (xv - mu) / sd;
        float term = -0.5f * tt * tt - ls - 0.91893853320467274f
                     - logf(1.f - pa * pa + 1e-6f);
        PA[r * 130 + j]   = pa;
        TERM[r * 130 + j] = term;
    }
    __syncthreads();

    {
        int r = tid >> 4;
        int i = tid & 15;
        float sp = 0.f, st = 0.f;
        for (int j = i; j < 129; j += 16) {
            sp += PA[r * 130 + j];
            st += TERM[r * 130 + j];
        }
        for (int off = 8; off > 0; off >>= 1) {
            sp += __shfl_down(sp, off, 16);
            st += __shfl_down(st, off, 16);
        }
        if (i == 0) { ROWSUM[r] = sp + 129.f; ROWLOG[r] = st; }
    }
    __syncthreads();

    for (int idx = tid; idx < 16 * 129; idx += 256) {
        int r = idx & 15;
        int j = idx >> 4;
        out[(size_t)(b0 + r) * 129 + j] = (PA[r * 130 + j] + 1.f) / ROWSUM[r];
    }
    if (tid < 16)
        out[(size_t)4096 * 129 + b0 + tid] = ROWLOG[tid];
}

// ---------------------------------------------------------------------------
extern "C" void kernel_launch(void* const* d_in, const int* in_sizes, int n_in,
                              void* d_out, int out_size, void* d_ws, size_t ws_size,
                              hipStream_t stream)
{
    const float* x   = (const float*)d_in[0];
    const float* wv  = (const float*)d_in[1];
    const float* eps = (const float*)d_in[2];
    const float* c1w = (const float*)d_in[3];
    const float* c1b = (const float*)d_in[4];
    const float* c2w = (const float*)d_in[5];
    const float* c2b = (const float*)d_in[6];
    const float* Wih = (const float*)d_in[7];
    const float* Whh = (const float*)d_in[8];
    const float* bih = (const float*)d_in[9];
    const float* bhh = (const float*)d_in[10];
    const float* muw = (const float*)d_in[11];
    const float* mub = (const float*)d_in[12];
    const float* lsw = (const float*)d_in[13];
    const float* lsb = (const float*)d_in[14];

    float* ws   = (float*)d_ws;
    float* seq  = ws + SEQ_OFF;
    float* g    = ws + G_OFF;
    float* whhp = ws + WHHP_OFF;
    float* muwp = ws + MUWP_OFF;
    float* lswp = ws + LSWP_OFF;
    float* outp = (float*)d_out;

    const int prep_elems = 387 * 132 + 2 * (129 * 260);
    prep_pad<<<(prep_elems + 255) / 256, 256, 0, stream>>>(Whh, muw, lsw, ws);
    conv_fused<<<dim3(6, BTOT), 256, 0, stream>>>(x, c1w, c1b, c2w, c2b, seq);
    gru_kernel<<<BTOT / 16, 768, 0, stream>>>(seq, Wih, whhp, bih, bhh, g);
    head_kernel<<<BTOT / 16, 256, 0, stream>>>(g, wv, eps, muwp, lswp, mub, lsb, outp);
}